// Round 10
// baseline (85.161 us; speedup 1.0000x reference)
//
#include <hip/hip_runtime.h>
#include <hip/hip_bf16.h>

#define RES 7
#define NCH 256

// ws layout: 27,200,000 ushort bf16 NHWC levels, then a 4-byte job counter.
#define WS_BF16_ELEMS 27200000ull
#define CTR_OFFSET_BYTES 54400000ull

#define NJOBS 3336            // 417 hw128-tiles x 4 cgroups x 2 batches
#define JOBS_PER_BATCH 1668
#define JOBS_PER_CG 417

__device__ __forceinline__ unsigned short f32_to_bf16_rne(float f) {
    unsigned int u = __float_as_uint(f);
    u += 0x7fffu + ((u >> 16) & 1u);
    return (unsigned short)(u >> 16);
}

__device__ __forceinline__ unsigned int pack_bf16x2(float lo, float hi) {
    return (unsigned int)f32_to_bf16_rne(lo) | ((unsigned int)f32_to_bf16_rne(hi) << 16);
}

// ---------------------------------------------------------------------------
// Pass 1 v6: persistent work-stealing transpose. NCHW fp32 -> NHWC bf16.
// Job = 128 hw x 64 c (32KB read). 1024 blocks x 512 thr grab jobs from a
// global counter -> zero tail, continuous load issue across jobs.
// ---------------------------------------------------------------------------
__global__ __launch_bounds__(512) void transpose_ws_bf16(
    const float* __restrict__ f0, const float* __restrict__ f1,
    const float* __restrict__ f2, const float* __restrict__ f3,
    unsigned short* __restrict__ ws, unsigned int* __restrict__ counter)
{
    __shared__ unsigned short lds[128 * 68];   // [hw][64 ch + 4 pad]
    __shared__ int job_s;

    const int t  = threadIdx.x;
    const int hq = t & 31;       // hw quad: 32 quads = 128 hw
    const int cr = t >> 5;       // 0..15 channel-quad within 64-ch group

    for (;;) {
        if (t == 0) job_s = (int)atomicAdd(counter, 1u);
        __syncthreads();                 // also fences previous iter's LDS reads
        const int j = job_s;
        if (j >= NJOBS) break;

        const int b   = (j >= JOBS_PER_BATCH) ? 1 : 0;
        const int rem = j - b * JOBS_PER_BATCH;
        const int cg  = rem / JOBS_PER_CG;          // 0..3
        const int xt  = rem - cg * JOBS_PER_CG;     // 0..416

        // per-level hw128-tile prefix: l0:313, l1:79, l2:20, l3:5
        const int l    = (xt >= 313) + (xt >= 392) + (xt >= 412);
        const int base = (l == 0) ? 0 : (l == 1) ? 313 : (l == 2) ? 392 : 412;
        const int HW   = (l == 0) ? 40000 : (l == 1) ? 10000 : (l == 2) ? 2500 : 625;
        const float* __restrict__ src =
            (l == 0) ? f0 : (l == 1) ? f1 : (l == 2) ? f2 : f3;
        const size_t doff = (l == 0) ? 0u : (l == 1) ? 20480000u
                          : (l == 2) ? 25600000u : 26880000u;

        const int hw0 = (xt - base) * 128;
        const int c0b = 64 * cg;
        const int c0  = c0b + 4 * cr;
        const int hwq = hw0 + 4 * hq;

        const float* __restrict__ s    = src + (size_t)b * NCH * HW;
        unsigned short* __restrict__ d = ws + doff + (size_t)b * HW * NCH;

        float va[4][4];                  // [ch i][hw jj]
        if (hwq + 3 < HW) {
#pragma unroll
            for (int i = 0; i < 4; ++i) {
                const float4 f = *(const float4*)(s + (size_t)(c0 + i) * HW + hwq);
                va[i][0] = f.x; va[i][1] = f.y; va[i][2] = f.z; va[i][3] = f.w;
            }
        } else {
#pragma unroll
            for (int i = 0; i < 4; ++i)
#pragma unroll
                for (int jj = 0; jj < 4; ++jj)
                    va[i][jj] = (hwq + jj < HW) ? s[(size_t)(c0 + i) * HW + hwq + jj] : 0.0f;
        }
#pragma unroll
        for (int jj = 0; jj < 4; ++jj) {
            uint2 p;
            p.x = pack_bf16x2(va[0][jj], va[1][jj]);
            p.y = pack_bf16x2(va[2][jj], va[3][jj]);
            *(uint2*)&lds[(4 * hq + jj) * 68 + 4 * cr] = p;   // ds_write_b64
        }
        __syncthreads();

        // store: 2048 uint2; per wave-instr = 4 hw rows x full 128B segment
#pragma unroll
        for (int it = 0; it < 4; ++it) {
            const int idx = t + 512 * it;    // 0..2047
            const int row = idx >> 4;        // local hw 0..127
            const int u   = idx & 15;        // uint2 within 128B segment
            const int hw  = hw0 + row;
            if (hw < HW) {
                const uint2 p = *(const uint2*)&lds[row * 68 + 4 * u];
                *(uint2*)(d + (size_t)hw * NCH + c0b + 4 * u) = p;
            }
        }
    }
}

// ---------------------------------------------------------------------------
// Pass 2: one block per ROI, 512 threads (8 waves).
// Lane = channel-quad (uint2 = 4 bf16); bins strided over 8 groups.
// ---------------------------------------------------------------------------
__global__ __launch_bounds__(512) void roi_gather_nhwc_bf16(
    const unsigned short* __restrict__ ws,
    const float* __restrict__ boxes, const int* __restrict__ bidx,
    float* __restrict__ out)
{
    __shared__ float lds[49 * 260];

    const int r   = blockIdx.x;
    const int t   = threadIdx.x;
    const int cq  = t & 63;
    const int grp = t >> 6;

    const float bx1 = boxes[r * 4 + 0];
    const float by1 = boxes[r * 4 + 1];
    const float bx2 = boxes[r * 4 + 2];
    const float by2 = boxes[r * 4 + 3];

    const float area = fmaxf(bx2 - bx1, 0.0f) * fmaxf(by2 - by1, 0.0f);
    const float s    = sqrtf(area);
    const float lvlf = floorf(4.0f + log2f(s / 224.0f + 1e-6f));
    const int   lvl  = (int)(fminf(fmaxf(lvlf, 2.0f), 5.0f)) - 2;

    float scale; int H; size_t off;
    if      (lvl == 0) { scale = 0.25f;    H = 200; off = 0u; }
    else if (lvl == 1) { scale = 0.125f;   H = 100; off = 20480000u; }
    else if (lvl == 2) { scale = 0.0625f;  H = 50;  off = 25600000u; }
    else               { scale = 0.03125f; H = 25;  off = 26880000u; }
    const int W = H;

    const int b = bidx[r];
    const unsigned short* __restrict__ feat = ws + off + (size_t)b * H * W * NCH;

    const float x1 = bx1 * scale;
    const float y1 = by1 * scale;
    const float roi_w = fmaxf(bx2 * scale - x1, 1.0f);
    const float roi_h = fmaxf(by2 * scale - y1, 1.0f);
    const float bw = roi_w * (1.0f / RES);
    const float bh = roi_h * (1.0f / RES);

    for (int bin = grp; bin < 49; bin += 8) {
        const int py = bin / 7;
        const int px = bin - py * 7;

        float acc0 = 0.0f, acc1 = 0.0f, acc2 = 0.0f, acc3 = 0.0f;
#pragma unroll
        for (int sy = 0; sy < 2; ++sy) {
            const float pyf = (float)py + ((float)sy + 0.5f) * 0.5f;
            const float ysmp = y1 + pyf * bh;
            const bool  vy   = (ysmp >= -1.0f) && (ysmp <= (float)H);
            const float ycl  = fminf(fmaxf(ysmp, 0.0f), (float)(H - 1));
            const int   y0   = (int)floorf(ycl);
            const int   y1i  = min(y0 + 1, H - 1);
            const float ly   = ycl - (float)y0;
            const float hy   = 1.0f - ly;
#pragma unroll
            for (int sx = 0; sx < 2; ++sx) {
                const float pxf = (float)px + ((float)sx + 0.5f) * 0.5f;
                const float xsmp = x1 + pxf * bw;
                const bool  vx   = (xsmp >= -1.0f) && (xsmp <= (float)W);
                const float xcl  = fminf(fmaxf(xsmp, 0.0f), (float)(W - 1));
                const int   x0   = (int)floorf(xcl);
                const int   x1i  = min(x0 + 1, W - 1);
                const float lx   = xcl - (float)x0;
                const float hx   = 1.0f - lx;

                const float m   = (vy && vx) ? 1.0f : 0.0f;
                const float w00 = m * hy * hx;
                const float w01 = m * hy * lx;
                const float w10 = m * ly * hx;
                const float w11 = m * ly * lx;

                const uint2 u00 = *(const uint2*)(feat + ((size_t)(y0  * W + x0 )) * NCH + 4 * cq);
                const uint2 u01 = *(const uint2*)(feat + ((size_t)(y0  * W + x1i)) * NCH + 4 * cq);
                const uint2 u10 = *(const uint2*)(feat + ((size_t)(y1i * W + x0 )) * NCH + 4 * cq);
                const uint2 u11 = *(const uint2*)(feat + ((size_t)(y1i * W + x1i)) * NCH + 4 * cq);

                acc0 += w00 * __uint_as_float(u00.x << 16)
                      + w01 * __uint_as_float(u01.x << 16)
                      + w10 * __uint_as_float(u10.x << 16)
                      + w11 * __uint_as_float(u11.x << 16);
                acc1 += w00 * __uint_as_float(u00.x & 0xffff0000u)
                      + w01 * __uint_as_float(u01.x & 0xffff0000u)
                      + w10 * __uint_as_float(u10.x & 0xffff0000u)
                      + w11 * __uint_as_float(u11.x & 0xffff0000u);
                acc2 += w00 * __uint_as_float(u00.y << 16)
                      + w01 * __uint_as_float(u01.y << 16)
                      + w10 * __uint_as_float(u10.y << 16)
                      + w11 * __uint_as_float(u11.y << 16);
                acc3 += w00 * __uint_as_float(u00.y & 0xffff0000u)
                      + w01 * __uint_as_float(u01.y & 0xffff0000u)
                      + w10 * __uint_as_float(u10.y & 0xffff0000u)
                      + w11 * __uint_as_float(u11.y & 0xffff0000u);
            }
        }
        float4* dst = (float4*)&lds[bin * 260 + 4 * cq];
        *dst = make_float4(acc0 * 0.25f, acc1 * 0.25f, acc2 * 0.25f, acc3 * 0.25f);
    }

    __syncthreads();

    float* __restrict__ o = out + (size_t)r * (NCH * 49);
    for (int i = t; i < NCH * 49; i += 512) {
        const int ch = i / 49;
        const int bn = i - ch * 49;
        o[i] = lds[bn * 260 + ch];
    }
}

// ---------------------------------------------------------------------------
// Non-stealing transpose fallback (round-9 v5 style, fixed grid) if the
// counter slot doesn't fit in ws.
// ---------------------------------------------------------------------------
__global__ __launch_bounds__(512) void transpose_fixed_bf16(
    const float* __restrict__ f0, const float* __restrict__ f1,
    const float* __restrict__ f2, const float* __restrict__ f3,
    unsigned short* __restrict__ ws)
{
    __shared__ unsigned short lds[128 * 68];
    const int t  = threadIdx.x;
    const int hq = t & 31;
    const int cr = t >> 5;

    for (int j = blockIdx.x; j < NJOBS; j += gridDim.x) {
        const int b   = (j >= JOBS_PER_BATCH) ? 1 : 0;
        const int rem = j - b * JOBS_PER_BATCH;
        const int cg  = rem / JOBS_PER_CG;
        const int xt  = rem - cg * JOBS_PER_CG;

        const int l    = (xt >= 313) + (xt >= 392) + (xt >= 412);
        const int base = (l == 0) ? 0 : (l == 1) ? 313 : (l == 2) ? 392 : 412;
        const int HW   = (l == 0) ? 40000 : (l == 1) ? 10000 : (l == 2) ? 2500 : 625;
        const float* __restrict__ src =
            (l == 0) ? f0 : (l == 1) ? f1 : (l == 2) ? f2 : f3;
        const size_t doff = (l == 0) ? 0u : (l == 1) ? 20480000u
                          : (l == 2) ? 25600000u : 26880000u;

        const int hw0 = (xt - base) * 128;
        const int c0b = 64 * cg;
        const int c0  = c0b + 4 * cr;
        const int hwq = hw0 + 4 * hq;

        const float* __restrict__ s    = src + (size_t)b * NCH * HW;
        unsigned short* __restrict__ d = ws + doff + (size_t)b * HW * NCH;

        float va[4][4];
        if (hwq + 3 < HW) {
#pragma unroll
            for (int i = 0; i < 4; ++i) {
                const float4 f = *(const float4*)(s + (size_t)(c0 + i) * HW + hwq);
                va[i][0] = f.x; va[i][1] = f.y; va[i][2] = f.z; va[i][3] = f.w;
            }
        } else {
#pragma unroll
            for (int i = 0; i < 4; ++i)
#pragma unroll
                for (int jj = 0; jj < 4; ++jj)
                    va[i][jj] = (hwq + jj < HW) ? s[(size_t)(c0 + i) * HW + hwq + jj] : 0.0f;
        }
#pragma unroll
        for (int jj = 0; jj < 4; ++jj) {
            uint2 p;
            p.x = pack_bf16x2(va[0][jj], va[1][jj]);
            p.y = pack_bf16x2(va[2][jj], va[3][jj]);
            *(uint2*)&lds[(4 * hq + jj) * 68 + 4 * cr] = p;
        }
        __syncthreads();
#pragma unroll
        for (int it = 0; it < 4; ++it) {
            const int idx = t + 512 * it;
            const int row = idx >> 4;
            const int u   = idx & 15;
            const int hw  = hw0 + row;
            if (hw < HW) {
                const uint2 p = *(const uint2*)&lds[row * 68 + 4 * u];
                *(uint2*)(d + (size_t)hw * NCH + c0b + 4 * u) = p;
            }
        }
        __syncthreads();
    }
}

// ---------------------------------------------------------------------------
// Fallback (round-1 kernel) if d_ws is too small for the NHWC bf16 copy.
// ---------------------------------------------------------------------------
__global__ __launch_bounds__(256) void roi_align_fpn_kernel(
    const float* __restrict__ f0, const float* __restrict__ f1,
    const float* __restrict__ f2, const float* __restrict__ f3,
    const float* __restrict__ boxes, const int* __restrict__ bidx,
    float* __restrict__ out)
{
    const int r   = blockIdx.x;
    const int bin = blockIdx.y;
    const int c   = threadIdx.x;
    const int py  = bin / RES;
    const int px  = bin - py * RES;

    const float bx1 = boxes[r * 4 + 0];
    const float by1 = boxes[r * 4 + 1];
    const float bx2 = boxes[r * 4 + 2];
    const float by2 = boxes[r * 4 + 3];

    const float area = fmaxf(bx2 - bx1, 0.0f) * fmaxf(by2 - by1, 0.0f);
    const float s    = sqrtf(area);
    const float lvlf = floorf(4.0f + log2f(s / 224.0f + 1e-6f));
    const int   lvl  = (int)(fminf(fmaxf(lvlf, 2.0f), 5.0f)) - 2;

    const float scales[4] = {0.25f, 0.125f, 0.0625f, 0.03125f};
    const int   Hs[4]     = {200, 100, 50, 25};
    const float* feats[4] = {f0, f1, f2, f3};

    const float scale = scales[lvl];
    const int   H     = Hs[lvl];
    const int   W     = H;
    const float* feat = feats[lvl];

    const int b = bidx[r];

    const float x1 = bx1 * scale;
    const float y1 = by1 * scale;
    const float roi_w = fmaxf(bx2 * scale - x1, 1.0f);
    const float roi_h = fmaxf(by2 * scale - y1, 1.0f);
    const float bw = roi_w * (1.0f / RES);
    const float bh = roi_h * (1.0f / RES);

    const float* __restrict__ fc = feat + (size_t)(b * NCH + c) * H * W;

    float acc = 0.0f;
#pragma unroll
    for (int sy = 0; sy < 2; ++sy) {
        const float pyf = (float)py + ((float)sy + 0.5f) * 0.5f;
        const float ys  = y1 + pyf * bh;
        const bool  vy  = (ys >= -1.0f) && (ys <= (float)H);
        const float ycl = fminf(fmaxf(ys, 0.0f), (float)(H - 1));
        const int   y0  = (int)floorf(ycl);
        const int   y1i = min(y0 + 1, H - 1);
        const float ly  = ycl - (float)y0;
        const float hy  = 1.0f - ly;
#pragma unroll
        for (int sx = 0; sx < 2; ++sx) {
            const float pxf = (float)px + ((float)sx + 0.5f) * 0.5f;
            const float xs  = x1 + pxf * bw;
            const bool  vx  = (xs >= -1.0f) && (xs <= (float)W);
            const float xcl = fminf(fmaxf(xs, 0.0f), (float)(W - 1));
            const int   x0  = (int)floorf(xcl);
            const int   x1i = min(x0 + 1, W - 1);
            const float lx  = xcl - (float)x0;
            const float hx  = 1.0f - lx;

            const float v00 = fc[y0  * W + x0 ];
            const float v01 = fc[y0  * W + x1i];
            const float v10 = fc[y1i * W + x0 ];
            const float v11 = fc[y1i * W + x1i];

            const float v = v00 * (hy * hx) + v01 * (hy * lx)
                          + v10 * (ly * hx) + v11 * (ly * lx);
            if (vy && vx) acc += v;
        }
    }

    out[((size_t)r * NCH + c) * (RES * RES) + bin] = acc * 0.25f;
}

extern "C" void kernel_launch(void* const* d_in, const int* in_sizes, int n_in,
                              void* d_out, int out_size, void* d_ws, size_t ws_size,
                              hipStream_t stream)
{
    const float* f0    = (const float*)d_in[0];
    const float* f1    = (const float*)d_in[1];
    const float* f2    = (const float*)d_in[2];
    const float* f3    = (const float*)d_in[3];
    const float* boxes = (const float*)d_in[4];
    const int*   bidx  = (const int*)d_in[5];
    float* out = (float*)d_out;

    const int R = in_sizes[4] / 4;  // 512 boxes

    const size_t need_ws  = WS_BF16_ELEMS * sizeof(unsigned short);
    const size_t need_ctr = CTR_OFFSET_BYTES + sizeof(unsigned int);

    if (ws_size >= need_ws) {
        unsigned short* ws = (unsigned short*)d_ws;
        if (ws_size >= need_ctr) {
            unsigned int* counter = (unsigned int*)((char*)d_ws + CTR_OFFSET_BYTES);
            hipMemsetAsync(counter, 0, sizeof(unsigned int), stream);
            transpose_ws_bf16<<<dim3(1024), dim3(512), 0, stream>>>(
                f0, f1, f2, f3, ws, counter);
        } else {
            transpose_fixed_bf16<<<dim3(1024), dim3(512), 0, stream>>>(
                f0, f1, f2, f3, ws);
        }
        roi_gather_nhwc_bf16<<<dim3(R), dim3(512), 0, stream>>>(ws, boxes, bidx, out);
    } else {
        dim3 grid(R, RES * RES);
        roi_align_fpn_kernel<<<grid, dim3(NCH), 0, stream>>>(f0, f1, f2, f3, boxes, bidx, out);
    }
}

// Round 11
// 49.598 us; speedup vs baseline: 1.7170x; 1.7170x over previous
//
#include <hip/hip_runtime.h>
#include <hip/hip_bf16.h>

#define RES 7
#define NCH 256

__device__ __forceinline__ unsigned short f32_to_bf16_rne(float f) {
    unsigned int u = __float_as_uint(f);
    u += 0x7fffu + ((u >> 16) & 1u);
    return (unsigned short)(u >> 16);
}

__device__ __forceinline__ unsigned int pack_bf16x2(float lo, float hi) {
    return (unsigned int)f32_to_bf16_rne(lo) | ((unsigned int)f32_to_bf16_rne(hi) << 16);
}

// ---------------------------------------------------------------------------
// Pass 1 v8: NCHW fp32 -> NHWC bf16. Tile = 256 hw x 64 c per block, 512 thr.
// = v4, plus sched_barrier(0) between the 8-load cluster and the pack phase:
// the fence forbids the compiler from sinking loads into the consumers
// (round-9 counter evidence: VGPR stayed 24 -> loads were serialized ~2-deep).
// All 8 float4 loads (32 data VGPRs) must be in flight before the first pack.
// ---------------------------------------------------------------------------
__global__ __launch_bounds__(512) void transpose_all_bf16_v8(
    const float* __restrict__ f0, const float* __restrict__ f1,
    const float* __restrict__ f2, const float* __restrict__ f3,
    unsigned short* __restrict__ ws)
{
    __shared__ unsigned short lds[256 * 68];   // [hw][64 ch + 4 pad]

    const int xt = blockIdx.x;                 // 0..209
    const int cy = blockIdx.y;                 // 0..3  -> channels 64*cy..
    const int b  = blockIdx.z;

    // per-level hw-tile prefix (256 hw per tile): f0:157, f1:40, f2:10, f3:3
    const int l    = (xt >= 157) + (xt >= 197) + (xt >= 207);
    const int base = (l == 0) ? 0 : (l == 1) ? 157 : (l == 2) ? 197 : 207;
    const int HW   = (l == 0) ? 40000 : (l == 1) ? 10000 : (l == 2) ? 2500 : 625;
    const float* __restrict__ src =
        (l == 0) ? f0 : (l == 1) ? f1 : (l == 2) ? f2 : f3;
    const size_t doff = (l == 0) ? 0u : (l == 1) ? 20480000u
                      : (l == 2) ? 25600000u : 26880000u;

    const int hw0 = (xt - base) * 256;
    const int c0b = 64 * cy;

    const float* __restrict__ s    = src + (size_t)b * NCH * HW;
    unsigned short* __restrict__ d = ws + doff + (size_t)b * HW * NCH;

    const int t   = threadIdx.x;
    const int hq  = t & 63;       // wave-lane -> hw quad (full wave = 256 hw)
    const int cg  = t >> 6;       // wave id 0..7 -> channel group
    const int hwq = hw0 + 4 * hq;

    float va[2][4][4];            // [sweep][ch i][hw j]
    const bool full = (hwq + 3 < HW);
#pragma unroll
    for (int sweep = 0; sweep < 2; ++sweep) {
        const int c0 = c0b + 4 * (cg + 8 * sweep);
        if (full) {
#pragma unroll
            for (int i = 0; i < 4; ++i) {
                const float4 f = *(const float4*)(s + (size_t)(c0 + i) * HW + hwq);
                va[sweep][i][0] = f.x; va[sweep][i][1] = f.y;
                va[sweep][i][2] = f.z; va[sweep][i][3] = f.w;
            }
        } else {
#pragma unroll
            for (int i = 0; i < 4; ++i)
#pragma unroll
                for (int j = 0; j < 4; ++j)
                    va[sweep][i][j] = (hwq + j < HW) ? s[(size_t)(c0 + i) * HW + hwq + j] : 0.0f;
        }
    }

    // Fence: nothing below may be scheduled above; loads cannot sink.
    __builtin_amdgcn_sched_barrier(0);

#pragma unroll
    for (int sweep = 0; sweep < 2; ++sweep) {
        const int cl = 4 * (cg + 8 * sweep);
#pragma unroll
        for (int j = 0; j < 4; ++j) {
            uint2 p;
            p.x = pack_bf16x2(va[sweep][0][j], va[sweep][1][j]);
            p.y = pack_bf16x2(va[sweep][2][j], va[sweep][3][j]);
            *(uint2*)&lds[(4 * hq + j) * 68 + cl] = p;   // ds_write_b64
        }
    }
    __syncthreads();

    // store: 4096 uint2 total; per wave-instr = 4 hw rows x full 128B segment
#pragma unroll
    for (int j = 0; j < 8; ++j) {
        const int idx = t + 512 * j;     // 0..4095
        const int row = idx >> 4;        // local hw 0..255
        const int u   = idx & 15;        // uint2 within 128B row segment
        const int hw  = hw0 + row;
        if (hw < HW) {
            const uint2 p = *(const uint2*)&lds[row * 68 + 4 * u];
            *(uint2*)(d + (size_t)hw * NCH + c0b + 4 * u) = p;
        }
    }
}

// ---------------------------------------------------------------------------
// Pass 2: one block per ROI, 512 threads (8 waves).
// Lane = channel-quad (uint2 = 4 bf16); bins strided over 8 groups.
// ---------------------------------------------------------------------------
__global__ __launch_bounds__(512) void roi_gather_nhwc_bf16(
    const unsigned short* __restrict__ ws,
    const float* __restrict__ boxes, const int* __restrict__ bidx,
    float* __restrict__ out)
{
    __shared__ float lds[49 * 260];

    const int r   = blockIdx.x;
    const int t   = threadIdx.x;
    const int cq  = t & 63;
    const int grp = t >> 6;

    const float bx1 = boxes[r * 4 + 0];
    const float by1 = boxes[r * 4 + 1];
    const float bx2 = boxes[r * 4 + 2];
    const float by2 = boxes[r * 4 + 3];

    const float area = fmaxf(bx2 - bx1, 0.0f) * fmaxf(by2 - by1, 0.0f);
    const float s    = sqrtf(area);
    const float lvlf = floorf(4.0f + log2f(s / 224.0f + 1e-6f));
    const int   lvl  = (int)(fminf(fmaxf(lvlf, 2.0f), 5.0f)) - 2;

    float scale; int H; size_t off;
    if      (lvl == 0) { scale = 0.25f;    H = 200; off = 0u; }
    else if (lvl == 1) { scale = 0.125f;   H = 100; off = 20480000u; }
    else if (lvl == 2) { scale = 0.0625f;  H = 50;  off = 25600000u; }
    else               { scale = 0.03125f; H = 25;  off = 26880000u; }
    const int W = H;

    const int b = bidx[r];
    const unsigned short* __restrict__ feat = ws + off + (size_t)b * H * W * NCH;

    const float x1 = bx1 * scale;
    const float y1 = by1 * scale;
    const float roi_w = fmaxf(bx2 * scale - x1, 1.0f);
    const float roi_h = fmaxf(by2 * scale - y1, 1.0f);
    const float bw = roi_w * (1.0f / RES);
    const float bh = roi_h * (1.0f / RES);

    for (int bin = grp; bin < 49; bin += 8) {
        const int py = bin / 7;
        const int px = bin - py * 7;

        float acc0 = 0.0f, acc1 = 0.0f, acc2 = 0.0f, acc3 = 0.0f;
#pragma unroll
        for (int sy = 0; sy < 2; ++sy) {
            const float pyf = (float)py + ((float)sy + 0.5f) * 0.5f;
            const float ysmp = y1 + pyf * bh;
            const bool  vy   = (ysmp >= -1.0f) && (ysmp <= (float)H);
            const float ycl  = fminf(fmaxf(ysmp, 0.0f), (float)(H - 1));
            const int   y0   = (int)floorf(ycl);
            const int   y1i  = min(y0 + 1, H - 1);
            const float ly   = ycl - (float)y0;
            const float hy   = 1.0f - ly;
#pragma unroll
            for (int sx = 0; sx < 2; ++sx) {
                const float pxf = (float)px + ((float)sx + 0.5f) * 0.5f;
                const float xsmp = x1 + pxf * bw;
                const bool  vx   = (xsmp >= -1.0f) && (xsmp <= (float)W);
                const float xcl  = fminf(fmaxf(xsmp, 0.0f), (float)(W - 1));
                const int   x0   = (int)floorf(xcl);
                const int   x1i  = min(x0 + 1, W - 1);
                const float lx   = xcl - (float)x0;
                const float hx   = 1.0f - lx;

                const float m   = (vy && vx) ? 1.0f : 0.0f;
                const float w00 = m * hy * hx;
                const float w01 = m * hy * lx;
                const float w10 = m * ly * hx;
                const float w11 = m * ly * lx;

                const uint2 u00 = *(const uint2*)(feat + ((size_t)(y0  * W + x0 )) * NCH + 4 * cq);
                const uint2 u01 = *(const uint2*)(feat + ((size_t)(y0  * W + x1i)) * NCH + 4 * cq);
                const uint2 u10 = *(const uint2*)(feat + ((size_t)(y1i * W + x0 )) * NCH + 4 * cq);
                const uint2 u11 = *(const uint2*)(feat + ((size_t)(y1i * W + x1i)) * NCH + 4 * cq);

                acc0 += w00 * __uint_as_float(u00.x << 16)
                      + w01 * __uint_as_float(u01.x << 16)
                      + w10 * __uint_as_float(u10.x << 16)
                      + w11 * __uint_as_float(u11.x << 16);
                acc1 += w00 * __uint_as_float(u00.x & 0xffff0000u)
                      + w01 * __uint_as_float(u01.x & 0xffff0000u)
                      + w10 * __uint_as_float(u10.x & 0xffff0000u)
                      + w11 * __uint_as_float(u11.x & 0xffff0000u);
                acc2 += w00 * __uint_as_float(u00.y << 16)
                      + w01 * __uint_as_float(u01.y << 16)
                      + w10 * __uint_as_float(u10.y << 16)
                      + w11 * __uint_as_float(u11.y << 16);
                acc3 += w00 * __uint_as_float(u00.y & 0xffff0000u)
                      + w01 * __uint_as_float(u01.y & 0xffff0000u)
                      + w10 * __uint_as_float(u10.y & 0xffff0000u)
                      + w11 * __uint_as_float(u11.y & 0xffff0000u);
            }
        }
        float4* dst = (float4*)&lds[bin * 260 + 4 * cq];
        *dst = make_float4(acc0 * 0.25f, acc1 * 0.25f, acc2 * 0.25f, acc3 * 0.25f);
    }

    __syncthreads();

    float* __restrict__ o = out + (size_t)r * (NCH * 49);
    for (int i = t; i < NCH * 49; i += 512) {
        const int ch = i / 49;
        const int bn = i - ch * 49;
        o[i] = lds[bn * 260 + ch];
    }
}

// ---------------------------------------------------------------------------
// Fallback (round-1 kernel) if d_ws is too small for the NHWC bf16 copy.
// ---------------------------------------------------------------------------
__global__ __launch_bounds__(256) void roi_align_fpn_kernel(
    const float* __restrict__ f0, const float* __restrict__ f1,
    const float* __restrict__ f2, const float* __restrict__ f3,
    const float* __restrict__ boxes, const int* __restrict__ bidx,
    float* __restrict__ out)
{
    const int r   = blockIdx.x;
    const int bin = blockIdx.y;
    const int c   = threadIdx.x;
    const int py  = bin / RES;
    const int px  = bin - py * RES;

    const float bx1 = boxes[r * 4 + 0];
    const float by1 = boxes[r * 4 + 1];
    const float bx2 = boxes[r * 4 + 2];
    const float by2 = boxes[r * 4 + 3];

    const float area = fmaxf(bx2 - bx1, 0.0f) * fmaxf(by2 - by1, 0.0f);
    const float s    = sqrtf(area);
    const float lvlf = floorf(4.0f + log2f(s / 224.0f + 1e-6f));
    const int   lvl  = (int)(fminf(fmaxf(lvlf, 2.0f), 5.0f)) - 2;

    const float scales[4] = {0.25f, 0.125f, 0.0625f, 0.03125f};
    const int   Hs[4]     = {200, 100, 50, 25};
    const float* feats[4] = {f0, f1, f2, f3};

    const float scale = scales[lvl];
    const int   H     = Hs[lvl];
    const int   W     = H;
    const float* feat = feats[lvl];

    const int b = bidx[r];

    const float x1 = bx1 * scale;
    const float y1 = by1 * scale;
    const float roi_w = fmaxf(bx2 * scale - x1, 1.0f);
    const float roi_h = fmaxf(by2 * scale - y1, 1.0f);
    const float bw = roi_w * (1.0f / RES);
    const float bh = roi_h * (1.0f / RES);

    const float* __restrict__ fc = feat + (size_t)(b * NCH + c) * H * W;

    float acc = 0.0f;
#pragma unroll
    for (int sy = 0; sy < 2; ++sy) {
        const float pyf = (float)py + ((float)sy + 0.5f) * 0.5f;
        const float ys  = y1 + pyf * bh;
        const bool  vy  = (ys >= -1.0f) && (ys <= (float)H);
        const float ycl = fminf(fmaxf(ys, 0.0f), (float)(H - 1));
        const int   y0  = (int)floorf(ycl);
        const int   y1i = min(y0 + 1, H - 1);
        const float ly  = ycl - (float)y0;
        const float hy  = 1.0f - ly;
#pragma unroll
        for (int sx = 0; sx < 2; ++sx) {
            const float pxf = (float)px + ((float)sx + 0.5f) * 0.5f;
            const float xs  = x1 + pxf * bw;
            const bool  vx  = (xs >= -1.0f) && (xs <= (float)W);
            const float xcl = fminf(fmaxf(xs, 0.0f), (float)(W - 1));
            const int   x0  = (int)floorf(xcl);
            const int   x1i = min(x0 + 1, W - 1);
            const float lx  = xcl - (float)x0;
            const float hx  = 1.0f - lx;

            const float v00 = fc[y0  * W + x0 ];
            const float v01 = fc[y0  * W + x1i];
            const float v10 = fc[y1i * W + x0 ];
            const float v11 = fc[y1i * W + x1i];

            const float v = v00 * (hy * hx) + v01 * (hy * lx)
                          + v10 * (ly * hx) + v11 * (ly * lx);
            if (vy && vx) acc += v;
        }
    }

    out[((size_t)r * NCH + c) * (RES * RES) + bin] = acc * 0.25f;
}

extern "C" void kernel_launch(void* const* d_in, const int* in_sizes, int n_in,
                              void* d_out, int out_size, void* d_ws, size_t ws_size,
                              hipStream_t stream)
{
    const float* f0    = (const float*)d_in[0];
    const float* f1    = (const float*)d_in[1];
    const float* f2    = (const float*)d_in[2];
    const float* f3    = (const float*)d_in[3];
    const float* boxes = (const float*)d_in[4];
    const int*   bidx  = (const int*)d_in[5];
    float* out = (float*)d_out;

    const int R = in_sizes[4] / 4;  // 512 boxes

    const size_t need = 27200000ull * sizeof(unsigned short);  // bf16 NHWC copy

    if (ws_size >= need) {
        unsigned short* ws = (unsigned short*)d_ws;
        transpose_all_bf16_v8<<<dim3(210, 4, 2), dim3(512), 0, stream>>>(f0, f1, f2, f3, ws);
        roi_gather_nhwc_bf16<<<dim3(R), dim3(512), 0, stream>>>(ws, boxes, bidx, out);
    } else {
        dim3 grid(R, RES * RES);
        roi_align_fpn_kernel<<<grid, dim3(NCH), 0, stream>>>(f0, f1, f2, f3, boxes, bidx, out);
    }
}